// Round 14
// baseline (1964.390 us; speedup 1.0000x reference)
//
#include <hip/hip_runtime.h>

#define EMBED 2560
#define HEADS 8
#define HDIM  320
#define BATCH 2
#define SEQ   2048
#define MTOT  (BATCH*SEQ)   // 4096
#define FTOT  (3*EMBED)     // 7680

using bf = __bf16;
typedef __bf16 bf16x8 __attribute__((ext_vector_type(8)));
typedef float  f32x4  __attribute__((ext_vector_type(4)));
typedef short  s16x8  __attribute__((ext_vector_type(8)));
typedef float  f32x4v __attribute__((ext_vector_type(4)));

__device__ __forceinline__ void gl_lds16(const bf* g, bf* l) {
    __builtin_amdgcn_global_load_lds(
        (const __attribute__((address_space(1))) void*)g,
        (__attribute__((address_space(3))) void*)l,
        16, 0, 0);
}

// ---------------- fused fp32 -> bf16 convert ----------------
__global__ void cvt_all(const float* __restrict__ x, const float* __restrict__ wq,
                        const float* __restrict__ wo, bf* __restrict__ xb,
                        bf* __restrict__ wqb, bf* __restrict__ wob) {
    const int N1 = MTOT*EMBED/8, N2 = FTOT*EMBED/8, N3 = EMBED*EMBED/8;
    const int stride = gridDim.x*blockDim.x;
    for (int c = blockIdx.x*blockDim.x + threadIdx.x; c < N1+N2+N3; c += stride) {
        const float* s; bf* d; int o = c;
        if (c < N1)           { s = x;  d = xb;  }
        else if (c < N1+N2)   { s = wq; d = wqb; o = c - N1; }
        else                  { s = wo; d = wob; o = c - N1 - N2; }
        f32x4v a = *reinterpret_cast<const f32x4v*>(s + (size_t)o*8);
        f32x4v b = *reinterpret_cast<const f32x4v*>(s + (size_t)o*8 + 4);
        bf16x8 r;
        r[0]=(bf)a[0]; r[1]=(bf)a[1]; r[2]=(bf)a[2]; r[3]=(bf)a[3];
        r[4]=(bf)b[0]; r[5]=(bf)b[1]; r[6]=(bf)b[2]; r[7]=(bf)b[3];
        *reinterpret_cast<bf16x8*>(d + (size_t)o*8) = r;
    }
}

// ====== 8-phase 256x256 NT GEMM, BK=32: 64 KB LDS -> 2 blocks/CU (TLP) ======
// r8 schedule/barriers/vmcnt logic, halved K-step. Linear LDS (64B rows are
// bank-floor-optimal for b128 reads; no swizzle needed). XCD supertile raster.
template<bool OUTBF>
__global__ __launch_bounds__(512, 4)
void gemm256(const bf* __restrict__ A, const bf* __restrict__ B,
             const float* __restrict__ bias, void* __restrict__ Cp,
             int M, int N, int K) {
    __shared__ __align__(16) bf AsL[2][2][4096];
    __shared__ __align__(16) bf BsL[2][2][4096];
    const int tid = threadIdx.x, lane = tid & 63, wid = tid >> 6;
    const int wr = wid >> 2, wc = wid & 3;
    const int l15 = lane & 15, l4 = lane >> 4;

    int mb, nb;
    const int i = blockIdx.y*gridDim.x + blockIdx.x;
    if ((gridDim.y == 16) && ((gridDim.x & 1) == 0)) {
        const int xcd = i & 7, j = i >> 3;
        const int pc = xcd & 1, pr = xcd >> 1;
        nb = pc*(gridDim.x >> 1) + (j >> 2);
        mb = pr*4 + (j & 3);
    } else {
        const int nwg = gridDim.x*gridDim.y;
        int bid = ((nwg & 7) == 0) ? (i & 7)*(nwg >> 3) + (i >> 3) : i;
        mb = bid / gridDim.x; nb = bid % gridDim.x;
    }
    const int m0 = mb*256, n0 = nb*256;
    const int NT = K >> 5;

    // staging: half-tile = 128 rows x 32 cols = 512 granules of 16B; granule g=tid
    // <-> (row=g>>2, kg=g&3); LDS linear; 1 gl_lds per thread per half-tile.
    const unsigned aOff = (unsigned)(tid >> 2)*K + (unsigned)((tid & 3)*8);
    const bf* Ap = A + (size_t)m0*K;
    const bf* Bp = B + (size_t)n0*K;

    auto stA = [&](int bb, int h, int kt) {
        gl_lds16(Ap + (size_t)h*128*K + (size_t)kt*32 + aOff, &AsL[bb][h][wid*512]);
    };
    auto stB = [&](int bb, int h, int kt) {
        gl_lds16(Bp + (size_t)h*128*K + (size_t)kt*32 + aOff, &BsL[bb][h][wid*512]);
    };

    f32x4 acc[8][4] = {};
    bf16x8 aR[4], bR0[2], bR1[2];

    // prologue: B0,A0,B1 staged; wait first 4 (all of kt=0)
    stB(0,0,0); stB(0,1,0); stA(0,0,0); stA(0,1,0); stB(1,0,1); stB(1,1,1);
    asm volatile("s_waitcnt vmcnt(2)" ::: "memory");
    __builtin_amdgcn_s_barrier();

    const int brow0 = (wc & 1)*64;
    for (int kt = 0; kt < NT; ++kt) {
        const int bb = kt & 1;
        const bf* Ab = &AsL[bb][wr][0];
        const bf* Bb = &BsL[bb][wc >> 1][0];

        // ---- phase 1: A-lo (4 reads) + B0 (2). stage A(kt+1,h0).
        #pragma unroll
        for (int mi = 0; mi < 4; ++mi)
            aR[mi] = *reinterpret_cast<const bf16x8*>(&Ab[(mi*16 + l15)*32 + l4*8]);
        #pragma unroll
        for (int ni = 0; ni < 2; ++ni)
            bR0[ni] = *reinterpret_cast<const bf16x8*>(&Bb[(brow0 + ni*16 + l15)*32 + l4*8]);
        if (kt + 1 < NT) stA(bb^1, 0, kt+1);
        __builtin_amdgcn_s_barrier();
        asm volatile("s_waitcnt lgkmcnt(0)" ::: "memory");
        __builtin_amdgcn_sched_barrier(0);
        __builtin_amdgcn_s_setprio(1);
        #pragma unroll
        for (int mi = 0; mi < 4; ++mi)
            #pragma unroll
            for (int ni = 0; ni < 2; ++ni)
                acc[mi][ni] = __builtin_amdgcn_mfma_f32_16x16x32_bf16(aR[mi], bR0[ni], acc[mi][ni], 0, 0, 0);
        __builtin_amdgcn_s_setprio(0);
        __builtin_amdgcn_s_barrier();

        // ---- phase 2: B1 (2 reads). stage A(kt+1,h1).
        #pragma unroll
        for (int ni = 0; ni < 2; ++ni)
            bR1[ni] = *reinterpret_cast<const bf16x8*>(&Bb[(brow0 + 32 + ni*16 + l15)*32 + l4*8]);
        if (kt + 1 < NT) stA(bb^1, 1, kt+1);
        __builtin_amdgcn_s_barrier();
        asm volatile("s_waitcnt lgkmcnt(0)" ::: "memory");
        __builtin_amdgcn_sched_barrier(0);
        __builtin_amdgcn_s_setprio(1);
        #pragma unroll
        for (int mi = 0; mi < 4; ++mi)
            #pragma unroll
            for (int ni = 0; ni < 2; ++ni)
                acc[mi][2+ni] = __builtin_amdgcn_mfma_f32_16x16x32_bf16(aR[mi], bR1[ni], acc[mi][2+ni], 0, 0, 0);
        __builtin_amdgcn_s_setprio(0);
        __builtin_amdgcn_s_barrier();

        // ---- phase 3: A-hi (4 reads, overwrite aR). stage B(kt+2,h0).
        #pragma unroll
        for (int mi = 0; mi < 4; ++mi)
            aR[mi] = *reinterpret_cast<const bf16x8*>(&Ab[(64 + mi*16 + l15)*32 + l4*8]);
        if (kt + 2 < NT) stB(bb, 0, kt+2);
        __builtin_amdgcn_s_barrier();
        asm volatile("s_waitcnt lgkmcnt(0)" ::: "memory");
        __builtin_amdgcn_sched_barrier(0);
        __builtin_amdgcn_s_setprio(1);
        #pragma unroll
        for (int mi = 0; mi < 4; ++mi)
            #pragma unroll
            for (int ni = 0; ni < 2; ++ni)
                acc[4+mi][2+ni] = __builtin_amdgcn_mfma_f32_16x16x32_bf16(aR[mi], bR1[ni], acc[4+mi][2+ni], 0, 0, 0);
        __builtin_amdgcn_s_setprio(0);
        __builtin_amdgcn_s_barrier();

        // ---- phase 4: no reads. stage B(kt+2,h1). counted vmcnt.
        if (kt + 2 < NT) stB(bb, 1, kt+2);
        if (kt >= NT-2) asm volatile("s_waitcnt vmcnt(0)" ::: "memory");
        else            asm volatile("s_waitcnt vmcnt(2)" ::: "memory");
        __builtin_amdgcn_s_barrier();
        __builtin_amdgcn_s_setprio(1);
        #pragma unroll
        for (int mi = 0; mi < 4; ++mi)
            #pragma unroll
            for (int ni = 0; ni < 2; ++ni)
                acc[4+mi][ni] = __builtin_amdgcn_mfma_f32_16x16x32_bf16(aR[mi], bR0[ni], acc[4+mi][ni], 0, 0, 0);
        __builtin_amdgcn_s_setprio(0);
        __builtin_amdgcn_s_barrier();
    }

    const int cr0 = m0 + wr*128, cc0 = n0 + wc*64;
    #pragma unroll
    for (int NI = 0; NI < 4; ++NI) {
        int colg = cc0 + NI*16 + l15;
        float bv = bias[colg];
        #pragma unroll
        for (int MI = 0; MI < 8; ++MI)
            #pragma unroll
            for (int rr = 0; rr < 4; ++rr) {
                int rowg = cr0 + MI*16 + l4*4 + rr;
                float v = acc[MI][NI][rr] + bv;
                if (OUTBF) ((bf*)Cp)[(size_t)rowg*N + colg] = (bf)v;
                else       ((float*)Cp)[(size_t)rowg*N + colg] = v;
            }
    }
}

// ---------------- V repack: qkv[b,s,2E + h*D + d] -> vt[bh, d, s] ----------------
__global__ void repack_vt(const bf* __restrict__ qkv, bf* __restrict__ vt) {
    __shared__ bf tile[64][72];
    const int bh = blockIdx.z, b = bh >> 3, h = bh & 7;
    const int s0 = blockIdx.x*64, d0 = blockIdx.y*64;
    const int t = threadIdx.x;
    #pragma unroll
    for (int p = 0; p < 2; ++p) {
        int sr = (t >> 3) + p*32, ck = t & 7;
        s16x8 v = *reinterpret_cast<const s16x8*>(
            qkv + ((size_t)(b*SEQ + s0 + sr))*FTOT + 2*EMBED + h*HDIM + d0 + ck*8);
        *reinterpret_cast<s16x8*>(&tile[sr][ck*8]) = v;
    }
    __syncthreads();
    #pragma unroll
    for (int p = 0; p < 2; ++p) {
        int dr = (t >> 3) + p*32, ck = t & 7;
        bf16x8 r;
        #pragma unroll
        for (int j = 0; j < 8; ++j) r[j] = tile[ck*8 + j][dr];
        *reinterpret_cast<bf16x8*>(vt + ((size_t)bh*HDIM + d0 + dr)*SEQ + s0 + ck*8) = r;
    }
}

// ---------------- flash attention (r11-best: 8 waves, dbuf K/V, gl_lds) ----------------
__global__ __launch_bounds__(512, 2)
void attn_fwd(const bf* __restrict__ qkv, const bf* __restrict__ vt, bf* __restrict__ aout) {
    __shared__ bf Kls[2][32*320];
    __shared__ bf Vls[2][320*32];
    __shared__ bf Ps[8][16][40];
    const int bh = blockIdx.y, b = bh >> 3, h = bh & 7;
    const int tid = threadIdx.x, lane = tid & 63, wid = tid >> 6;
    const int qw = blockIdx.x*128 + wid*16;
    const int l15 = lane & 15, l4 = lane >> 4;
    const float scale = 0.05590169944f;

    const bf* gsrc[5];
    int ldsoff[5];
    size_t step;
    if (wid < 4) {
        step = (size_t)32*FTOT;
        #pragma unroll
        for (int i = 0; i < 5; ++i) {
            int g = wid*5 + i;
            int q = g*64 + lane;
            int r = q/40, cl = q - r*40;
            int cg = cl ^ (r & 7);
            gsrc[i] = qkv + (size_t)(b*SEQ + r)*FTOT + EMBED + h*HDIM + cg*8;
            ldsoff[i] = g*512;
        }
    } else {
        step = 32;
        #pragma unroll
        for (int i = 0; i < 5; ++i) {
            int g = wid*5 + i - 20;
            int q = g*64 + lane;
            int row = q >> 2, cl = q & 3;
            int cg = cl ^ ((row >> 1) & 3);
            gsrc[i] = vt + (size_t)bh*HDIM*SEQ + (size_t)row*SEQ + cg*8;
            ldsoff[i] = g*512;
        }
    }

    bf16x8 qf[10];
    const bf* qbase = qkv + ((size_t)(b*SEQ + qw + l15))*FTOT + h*HDIM + l4*8;
    #pragma unroll
    for (int d = 0; d < 10; ++d) qf[d] = *reinterpret_cast<const bf16x8*>(qbase + d*32);

    f32x4 o[20] = {};
    float mrow[4], lsum[4];
    #pragma unroll
    for (int r = 0; r < 4; ++r) { mrow[r] = -1e30f; lsum[r] = 0.f; }

    const int r7  = l15 & 7;
    const int vsw = (l4 ^ ((l15 >> 1) & 3))*8;

    {
        bf* lb = (wid < 4) ? &Kls[0][0] : &Vls[0][0];
        #pragma unroll
        for (int i = 0; i < 5; ++i) { gl_lds16(gsrc[i], lb + ldsoff[i]); gsrc[i] += step; }
    }
    __syncthreads();

    for (int kt = 0; kt < SEQ/32; ++kt) {
        const int bb = kt & 1;
        if (kt + 1 < SEQ/32) {
            bf* lb = (wid < 4) ? &Kls[bb^1][0] : &Vls[bb^1][0];
            #pragma unroll
            for (int i = 0; i < 5; ++i) { gl_lds16(gsrc[i], lb + ldsoff[i]); gsrc[i] += step; }
        }
        const bf* Kb = &Kls[bb][0];
        const bf* Vb = &Vls[bb][0];

        f32x4 sc[2] = {};
        #pragma unroll
        for (int kb = 0; kb < 2; ++kb) {
            const int Rbase = (kb*16 + l15)*320;
            #pragma unroll
            for (int d = 0; d < 10; ++d) {
                int c = (d*4 + l4) ^ r7;
                bf16x8 kf = *reinterpret_cast<const bf16x8*>(&Kb[Rbase + c*8]);
                sc[kb] = __builtin_amdgcn_mfma_f32_16x16x32_bf16(qf[d], kf, sc[kb], 0, 0, 0);
            }
        }

        float tmax[4];
        bool need = false;
        #pragma unroll
        for (int r = 0; r < 4; ++r) {
            float v = fmaxf(sc[0][r], sc[1][r])*scale;
            v = fmaxf(v, __shfl_xor(v, 1));
            v = fmaxf(v, __shfl_xor(v, 2));
            v = fmaxf(v, __shfl_xor(v, 4));
            v = fmaxf(v, __shfl_xor(v, 8));
            tmax[r] = v;
            need = need || (v > mrow[r] + 8.f);
        }
        if (__any(need)) {
            float alpha[4];
            #pragma unroll
            for (int r = 0; r < 4; ++r) {
                float nm = fmaxf(mrow[r], tmax[r]);
                alpha[r] = __expf(mrow[r] - nm);
                mrow[r] = nm;
                lsum[r] *= alpha[r];
            }
            #pragma unroll
            for (int c = 0; c < 20; ++c)
                #pragma unroll
                for (int r = 0; r < 4; ++r) o[c][r] *= alpha[r];
        }

        float ps[2][4];
        #pragma unroll
        for (int r = 0; r < 4; ++r) {
            float p0 = __expf(sc[0][r]*scale - mrow[r]);
            float p1 = __expf(sc[1][r]*scale - mrow[r]);
            ps[0][r] = p0; ps[1][r] = p1;
            lsum[r] += p0 + p1;
        }

        #pragma unroll
        for (int kb = 0; kb < 2; ++kb)
            #pragma unroll
            for (int r = 0; r < 4; ++r)
                Ps[wid][l4*4 + r][kb*16 + l15] = (bf)ps[kb][r];

        bf16x8 pf = *reinterpret_cast<const bf16x8*>(&Ps[wid][l15][l4*8]);
        #pragma unroll
        for (int c = 0; c < 20; ++c) {
            bf16x8 vf = *reinterpret_cast<const bf16x8*>(&Vb[(c*16 + l15)*32 + vsw]);
            o[c] = __builtin_amdgcn_mfma_f32_16x16x32_bf16(pf, vf, o[c], 0, 0, 0);
        }
        __syncthreads();
    }

    float inv[4];
    #pragma unroll
    for (int r = 0; r < 4; ++r) {
        float s = lsum[r];
        s += __shfl_xor(s, 1);
        s += __shfl_xor(s, 2);
        s += __shfl_xor(s, 4);
        s += __shfl_xor(s, 8);
        inv[r] = 1.f/s;
    }
    #pragma unroll
    for (int c = 0; c < 20; ++c)
        #pragma unroll
        for (int r = 0; r < 4; ++r) {
            size_t idx = ((size_t)(b*SEQ + qw + l4*4 + r))*EMBED + h*HDIM + c*16 + l15;
            aout[idx] = (bf)(o[c][r]*inv[r]);
        }
}

// ---------------- launch ----------------
extern "C" void kernel_launch(void* const* d_in, const int* in_sizes, int n_in,
                              void* d_out, int out_size, void* d_ws, size_t ws_size,
                              hipStream_t stream) {
    const float* x    = (const float*)d_in[0];
    const float* Wqkv = (const float*)d_in[1];
    const float* bqkv = (const float*)d_in[2];
    const float* Wout = (const float*)d_in[3];
    const float* bout = (const float*)d_in[4];
    float* out = (float*)d_out;

    char* ws = (char*)d_ws;
    bf* xb    = (bf*)(ws);                         // 20,971,520 B
    bf* wqkvb = (bf*)(ws + 20971520);              // 39,321,600 B
    bf* woutb = (bf*)(ws + 60293120);              // 13,107,200 B
    bf* qkvb  = (bf*)(ws + 73400320);              // 62,914,560 B
    bf* vtb   = (bf*)(ws + 136314880);             // 20,971,520 B -> total 157,286,400
    bf* attnb = xb;                                // alias: x consumed by gemm1

    cvt_all<<<2048, 256, 0, stream>>>(x, Wqkv, Wout, xb, wqkvb, woutb);
    gemm256<true ><<<dim3(FTOT/256,  MTOT/256), 512, 0, stream>>>(xb, wqkvb, bqkv, qkvb, MTOT, FTOT, EMBED);
    repack_vt<<<dim3(SEQ/64, HDIM/64, BATCH*HEADS), 256, 0, stream>>>(qkvb, vtb);
    attn_fwd<<<dim3(SEQ/128, BATCH*HEADS), 512, 0, stream>>>(qkvb, vtb, attnb);
    gemm256<false><<<dim3(EMBED/256, MTOT/256), 512, 0, stream>>>(attnb, woutb, bout, out, MTOT, EMBED, EMBED);
}

// Round 18
// 409.885 us; speedup vs baseline: 4.7925x; 4.7925x over previous
//
#include <hip/hip_runtime.h>

#define EMBED 2560
#define HEADS 8
#define HDIM  320
#define BATCH 2
#define SEQ   2048
#define MTOT  (BATCH*SEQ)   // 4096
#define FTOT  (3*EMBED)     // 7680

using bf = __bf16;
typedef __bf16 bf16x8 __attribute__((ext_vector_type(8)));
typedef float  f32x4  __attribute__((ext_vector_type(4)));
typedef short  s16x8  __attribute__((ext_vector_type(8)));
typedef float  f32x4v __attribute__((ext_vector_type(4)));

__device__ __forceinline__ void gl_lds16(const bf* g, bf* l) {
    __builtin_amdgcn_global_load_lds(
        (const __attribute__((address_space(1))) void*)g,
        (__attribute__((address_space(3))) void*)l,
        16, 0, 0);
}

// ---------------- fused fp32 -> bf16 convert ----------------
__global__ void cvt_all(const float* __restrict__ x, const float* __restrict__ wq,
                        const float* __restrict__ wo, bf* __restrict__ xb,
                        bf* __restrict__ wqb, bf* __restrict__ wob) {
    const int N1 = MTOT*EMBED/8, N2 = FTOT*EMBED/8, N3 = EMBED*EMBED/8;
    const int stride = gridDim.x*blockDim.x;
    for (int c = blockIdx.x*blockDim.x + threadIdx.x; c < N1+N2+N3; c += stride) {
        const float* s; bf* d; int o = c;
        if (c < N1)           { s = x;  d = xb;  }
        else if (c < N1+N2)   { s = wq; d = wqb; o = c - N1; }
        else                  { s = wo; d = wob; o = c - N1 - N2; }
        f32x4v a = *reinterpret_cast<const f32x4v*>(s + (size_t)o*8);
        f32x4v b = *reinterpret_cast<const f32x4v*>(s + (size_t)o*8 + 4);
        bf16x8 r;
        r[0]=(bf)a[0]; r[1]=(bf)a[1]; r[2]=(bf)a[2]; r[3]=(bf)a[3];
        r[4]=(bf)b[0]; r[5]=(bf)b[1]; r[6]=(bf)b[2]; r[7]=(bf)b[3];
        *reinterpret_cast<bf16x8*>(d + (size_t)o*8) = r;
    }
}

// ============ 8-phase 256x256 NT GEMM (r8 schedule, BK=64, 3-bit swizzle) ============
// XCD supertile raster ONLY for the QKV grid (30x16); proj (10x16) uses chunked
// swizzle (r15 ledger: supertile cost proj ~16us while saving QKV ~6us).
template<bool OUTBF>
__global__ __launch_bounds__(512, 2)
void gemm256(const bf* __restrict__ A, const bf* __restrict__ B,
             const float* __restrict__ bias, void* __restrict__ Cp,
             int M, int N, int K) {
    __shared__ __align__(16) bf AsL[2][2][8192];
    __shared__ __align__(16) bf BsL[2][2][8192];
    const int tid = threadIdx.x, lane = tid & 63, wid = tid >> 6;
    const int wr = wid >> 2, wc = wid & 3;
    const int l15 = lane & 15, l4 = lane >> 4;

    int mb, nb;
    const int i = blockIdx.y*gridDim.x + blockIdx.x;
    if ((gridDim.y == 16) && (gridDim.x == 30)) {
        const int xcd = i & 7, j = i >> 3;
        const int pc = xcd & 1, pr = xcd >> 1;
        nb = pc*(gridDim.x >> 1) + (j >> 2);
        mb = pr*4 + (j & 3);
    } else {
        const int nwg = gridDim.x*gridDim.y;
        int bid = ((nwg & 7) == 0) ? (i & 7)*(nwg >> 3) + (i >> 3) : i;
        mb = bid / gridDim.x; nb = bid % gridDim.x;
    }
    const int m0 = mb*256, n0 = nb*256;
    const int NT = K >> 6;

    unsigned aOff[2];
    #pragma unroll
    for (int j = 0; j < 2; ++j) {
        int q = (wid*2 + j)*64 + lane;
        int r = q >> 3, c = q & 7;
        aOff[j] = (unsigned)r*K + (unsigned)((c ^ (r & 7))*8);
    }
    const bf* Ap = A + (size_t)m0*K;
    const bf* Bp = B + (size_t)n0*K;

    auto stA = [&](int bb, int h, int kt) {
        bf* d = &AsL[bb][h][wid*1024];
        const bf* s = Ap + (size_t)h*128*K + (size_t)kt*64;
        gl_lds16(s + aOff[0], d);
        gl_lds16(s + aOff[1], d + 512);
    };
    auto stB = [&](int bb, int h, int kt) {
        bf* d = &BsL[bb][h][wid*1024];
        const bf* s = Bp + (size_t)h*128*K + (size_t)kt*64;
        gl_lds16(s + aOff[0], d);
        gl_lds16(s + aOff[1], d + 512);
    };

    f32x4 acc[8][4] = {};
    bf16x8 aR[4][2], bR0[2][2], bR1[2][2];

    stB(0,0,0); stB(0,1,0); stA(0,0,0); stA(0,1,0); stB(1,0,1); stB(1,1,1);
    asm volatile("s_waitcnt vmcnt(4)" ::: "memory");
    __builtin_amdgcn_s_barrier();

    const int brow0 = (wc & 1)*64;
    for (int kt = 0; kt < NT; ++kt) {
        const int bb = kt & 1;
        const bf* Ab = &AsL[bb][wr][0];
        const bf* Bb = &BsL[bb][wc >> 1][0];

        // ---- phase 1
        #pragma unroll
        for (int mi = 0; mi < 4; ++mi)
            #pragma unroll
            for (int kk = 0; kk < 2; ++kk) {
                int r = mi*16 + l15;
                int kg = kk*4 + l4;
                aR[mi][kk] = *reinterpret_cast<const bf16x8*>(&Ab[r*64 + ((kg ^ (r & 7))*8)]);
            }
        #pragma unroll
        for (int ni = 0; ni < 2; ++ni)
            #pragma unroll
            for (int kk = 0; kk < 2; ++kk) {
                int r = brow0 + ni*16 + l15;
                int kg = kk*4 + l4;
                bR0[ni][kk] = *reinterpret_cast<const bf16x8*>(&Bb[r*64 + ((kg ^ (r & 7))*8)]);
            }
        if (kt + 1 < NT) stA(bb^1, 0, kt+1);
        __builtin_amdgcn_s_barrier();
        asm volatile("s_waitcnt lgkmcnt(0)" ::: "memory");
        __builtin_amdgcn_sched_barrier(0);
        __builtin_amdgcn_s_setprio(1);
        #pragma unroll
        for (int mi = 0; mi < 4; ++mi)
            #pragma unroll
            for (int ni = 0; ni < 2; ++ni)
                #pragma unroll
                for (int kk = 0; kk < 2; ++kk)
                    acc[mi][ni] = __builtin_amdgcn_mfma_f32_16x16x32_bf16(aR[mi][kk], bR0[ni][kk], acc[mi][ni], 0, 0, 0);
        __builtin_amdgcn_s_setprio(0);
        __builtin_amdgcn_s_barrier();

        // ---- phase 2
        #pragma unroll
        for (int ni = 0; ni < 2; ++ni)
            #pragma unroll
            for (int kk = 0; kk < 2; ++kk) {
                int r = brow0 + 32 + ni*16 + l15;
                int kg = kk*4 + l4;
                bR1[ni][kk] = *reinterpret_cast<const bf16x8*>(&Bb[r*64 + ((kg ^ (r & 7))*8)]);
            }
        if (kt + 1 < NT) stA(bb^1, 1, kt+1);
        __builtin_amdgcn_s_barrier();
        asm volatile("s_waitcnt lgkmcnt(0)" ::: "memory");
        __builtin_amdgcn_sched_barrier(0);
        __builtin_amdgcn_s_setprio(1);
        #pragma unroll
        for (int mi = 0; mi < 4; ++mi)
            #pragma unroll
            for (int ni = 0; ni < 2; ++ni)
                #pragma unroll
                for (int kk = 0; kk < 2; ++kk)
                    acc[mi][2+ni] = __builtin_amdgcn_mfma_f32_16x16x32_bf16(aR[mi][kk], bR1[ni][kk], acc[mi][2+ni], 0, 0, 0);
        __builtin_amdgcn_s_setprio(0);
        __builtin_amdgcn_s_barrier();

        // ---- phase 3
        #pragma unroll
        for (int mi = 0; mi < 4; ++mi)
            #pragma unroll
            for (int kk = 0; kk < 2; ++kk) {
                int r = 64 + mi*16 + l15;
                int kg = kk*4 + l4;
                aR[mi][kk] = *reinterpret_cast<const bf16x8*>(&Ab[r*64 + ((kg ^ (r & 7))*8)]);
            }
        if (kt + 2 < NT) stB(bb, 0, kt+2);
        __builtin_amdgcn_s_barrier();
        asm volatile("s_waitcnt lgkmcnt(0)" ::: "memory");
        __builtin_amdgcn_sched_barrier(0);
        __builtin_amdgcn_s_setprio(1);
        #pragma unroll
        for (int mi = 0; mi < 4; ++mi)
            #pragma unroll
            for (int ni = 0; ni < 2; ++ni)
                #pragma unroll
                for (int kk = 0; kk < 2; ++kk)
                    acc[4+mi][2+ni] = __builtin_amdgcn_mfma_f32_16x16x32_bf16(aR[mi][kk], bR1[ni][kk], acc[4+mi][2+ni], 0, 0, 0);
        __builtin_amdgcn_s_setprio(0);
        __builtin_amdgcn_s_barrier();

        // ---- phase 4
        if (kt + 2 < NT) stB(bb, 1, kt+2);
        if (kt >= NT-2) asm volatile("s_waitcnt vmcnt(0)" ::: "memory");
        else            asm volatile("s_waitcnt vmcnt(4)" ::: "memory");
        __builtin_amdgcn_s_barrier();
        __builtin_amdgcn_s_setprio(1);
        #pragma unroll
        for (int mi = 0; mi < 4; ++mi)
            #pragma unroll
            for (int ni = 0; ni < 2; ++ni)
                #pragma unroll
                for (int kk = 0; kk < 2; ++kk)
                    acc[4+mi][ni] = __builtin_amdgcn_mfma_f32_16x16x32_bf16(aR[mi][kk], bR0[ni][kk], acc[4+mi][ni], 0, 0, 0);
        __builtin_amdgcn_s_setprio(0);
        __builtin_amdgcn_s_barrier();
    }

    const int cr0 = m0 + wr*128, cc0 = n0 + wc*64;
    #pragma unroll
    for (int NI = 0; NI < 4; ++NI) {
        int colg = cc0 + NI*16 + l15;
        float bv = bias[colg];
        #pragma unroll
        for (int MI = 0; MI < 8; ++MI)
            #pragma unroll
            for (int rr = 0; rr < 4; ++rr) {
                int rowg = cr0 + MI*16 + l4*4 + rr;
                float v = acc[MI][NI][rr] + bv;
                if (OUTBF) ((bf*)Cp)[(size_t)rowg*N + colg] = (bf)v;
                else       ((float*)Cp)[(size_t)rowg*N + colg] = v;
            }
    }
}

// ---------------- V repack: qkv[b,s,2E + h*D + d] -> vt[bh, d, s] ----------------
__global__ void repack_vt(const bf* __restrict__ qkv, bf* __restrict__ vt) {
    __shared__ bf tile[64][72];
    const int bh = blockIdx.z, b = bh >> 3, h = bh & 7;
    const int s0 = blockIdx.x*64, d0 = blockIdx.y*64;
    const int t = threadIdx.x;
    #pragma unroll
    for (int p = 0; p < 2; ++p) {
        int sr = (t >> 3) + p*32, ck = t & 7;
        s16x8 v = *reinterpret_cast<const s16x8*>(
            qkv + ((size_t)(b*SEQ + s0 + sr))*FTOT + 2*EMBED + h*HDIM + d0 + ck*8);
        *reinterpret_cast<s16x8*>(&tile[sr][ck*8]) = v;
    }
    __syncthreads();
    #pragma unroll
    for (int p = 0; p < 2; ++p) {
        int dr = (t >> 3) + p*32, ck = t & 7;
        bf16x8 r;
        #pragma unroll
        for (int j = 0; j < 8; ++j) r[j] = tile[ck*8 + j][dr];
        *reinterpret_cast<bf16x8*>(vt + ((size_t)bh*HDIM + d0 + dr)*SEQ + s0 + ck*8) = r;
    }
}

// ---------------- flash attention (r5/r11 v3: 8 waves, dbuf K/V, gl_lds) ----------------
__global__ __launch_bounds__(512, 2)
void attn_fwd(const bf* __restrict__ qkv, const bf* __restrict__ vt, bf* __restrict__ aout) {
    __shared__ bf Kls[2][32*320];
    __shared__ bf Vls[2][320*32];
    __shared__ bf Ps[8][16][40];
    const int bh = blockIdx.y, b = bh >> 3, h = bh & 7;
    const int tid = threadIdx.x, lane = tid & 63, wid = tid >> 6;
    const int qw = blockIdx.x*128 + wid*16;
    const int l15 = lane & 15, l4 = lane >> 4;
    const float scale = 0.05590169944f;

    const bf* gsrc[5];
    int ldsoff[5];
    size_t step;
    if (wid < 4) {
        step = (size_t)32*FTOT;
        #pragma unroll
        for (int i = 0; i < 5; ++i) {
            int g = wid*5 + i;
            int q = g*64 + lane;
            int r = q/40, cl = q - r*40;
            int cg = cl ^ (r & 7);
            gsrc[i] = qkv + (size_t)(b*SEQ + r)*FTOT + EMBED + h*HDIM + cg*8;
            ldsoff[i] = g*512;
        }
    } else {
        step = 32;
        #pragma unroll
        for (int i = 0; i < 5; ++i) {
            int g = wid*5 + i - 20;
            int q = g*64 + lane;
            int row = q >> 2, cl = q & 3;
            int cg = cl ^ ((row >> 1) & 3);
            gsrc[i] = vt + (size_t)bh*HDIM*SEQ + (size_t)row*SEQ + cg*8;
            ldsoff[i] = g*512;
        }
    }

    bf16x8 qf[10];
    const bf* qbase = qkv + ((size_t)(b*SEQ + qw + l15))*FTOT + h*HDIM + l4*8;
    #pragma unroll
    for (int d = 0; d < 10; ++d) qf[d] = *reinterpret_cast<const bf16x8*>(qbase + d*32);

    f32x4 o[20] = {};
    float mrow[4], lsum[4];
    #pragma unroll
    for (int r = 0; r < 4; ++r) { mrow[r] = -1e30f; lsum[r] = 0.f; }

    const int r7  = l15 & 7;
    const int vsw = (l4 ^ ((l15 >> 1) & 3))*8;

    {
        bf* lb = (wid < 4) ? &Kls[0][0] : &Vls[0][0];
        #pragma unroll
        for (int i = 0; i < 5; ++i) { gl_lds16(gsrc[i], lb + ldsoff[i]); gsrc[i] += step; }
    }
    __syncthreads();

    for (int kt = 0; kt < SEQ/32; ++kt) {
        const int bb = kt & 1;
        if (kt + 1 < SEQ/32) {
            bf* lb = (wid < 4) ? &Kls[bb^1][0] : &Vls[bb^1][0];
            #pragma unroll
            for (int i = 0; i < 5; ++i) { gl_lds16(gsrc[i], lb + ldsoff[i]); gsrc[i] += step; }
        }
        const bf* Kb = &Kls[bb][0];
        const bf* Vb = &Vls[bb][0];

        f32x4 sc[2] = {};
        #pragma unroll
        for (int kb = 0; kb < 2; ++kb) {
            const int Rbase = (kb*16 + l15)*320;
            #pragma unroll
            for (int d = 0; d < 10; ++d) {
                int c = (d*4 + l4) ^ r7;
                bf16x8 kf = *reinterpret_cast<const bf16x8*>(&Kb[Rbase + c*8]);
                sc[kb] = __builtin_amdgcn_mfma_f32_16x16x32_bf16(qf[d], kf, sc[kb], 0, 0, 0);
            }
        }

        float tmax[4];
        bool need = false;
        #pragma unroll
        for (int r = 0; r < 4; ++r) {
            float v = fmaxf(sc[0][r], sc[1][r])*scale;
            v = fmaxf(v, __shfl_xor(v, 1));
            v = fmaxf(v, __shfl_xor(v, 2));
            v = fmaxf(v, __shfl_xor(v, 4));
            v = fmaxf(v, __shfl_xor(v, 8));
            tmax[r] = v;
            need = need || (v > mrow[r] + 8.f);
        }
        if (__any(need)) {
            float alpha[4];
            #pragma unroll
            for (int r = 0; r < 4; ++r) {
                float nm = fmaxf(mrow[r], tmax[r]);
                alpha[r] = __expf(mrow[r] - nm);
                mrow[r] = nm;
                lsum[r] *= alpha[r];
            }
            #pragma unroll
            for (int c = 0; c < 20; ++c)
                #pragma unroll
                for (int r = 0; r < 4; ++r) o[c][r] *= alpha[r];
        }

        float ps[2][4];
        #pragma unroll
        for (int r = 0; r < 4; ++r) {
            float p0 = __expf(sc[0][r]*scale - mrow[r]);
            float p1 = __expf(sc[1][r]*scale - mrow[r]);
            ps[0][r] = p0; ps[1][r] = p1;
            lsum[r] += p0 + p1;
        }

        #pragma unroll
        for (int kb = 0; kb < 2; ++kb)
            #pragma unroll
            for (int r = 0; r < 4; ++r)
                Ps[wid][l4*4 + r][kb*16 + l15] = (bf)ps[kb][r];

        bf16x8 pf = *reinterpret_cast<const bf16x8*>(&Ps[wid][l15][l4*8]);
        #pragma unroll
        for (int c = 0; c < 20; ++c) {
            bf16x8 vf = *reinterpret_cast<const bf16x8*>(&Vb[(c*16 + l15)*32 + vsw]);
            o[c] = __builtin_amdgcn_mfma_f32_16x16x32_bf16(pf, vf, o[c], 0, 0, 0);
        }
        __syncthreads();
    }

    float inv[4];
    #pragma unroll
    for (int r = 0; r < 4; ++r) {
        float s = lsum[r];
        s += __shfl_xor(s, 1);
        s += __shfl_xor(s, 2);
        s += __shfl_xor(s, 4);
        s += __shfl_xor(s, 8);
        inv[r] = 1.f/s;
    }
    #pragma unroll
    for (int c = 0; c < 20; ++c)
        #pragma unroll
        for (int r = 0; r < 4; ++r) {
            size_t idx = ((size_t)(b*SEQ + qw + l4*4 + r))*EMBED + h*HDIM + c*16 + l15;
            aout[idx] = (bf)(o[c][r]*inv[r]);
        }
}

// ---------------- launch ----------------
extern "C" void kernel_launch(void* const* d_in, const int* in_sizes, int n_in,
                              void* d_out, int out_size, void* d_ws, size_t ws_size,
                              hipStream_t stream) {
    const float* x    = (const float*)d_in[0];
    const float* Wqkv = (const float*)d_in[1];
    const float* bqkv = (const float*)d_in[2];
    const float* Wout = (const float*)d_in[3];
    const float* bout = (const float*)d_in[4];
    float* out = (float*)d_out;

    char* ws = (char*)d_ws;
    bf* xb    = (bf*)(ws);                         // 20,971,520 B
    bf* wqkvb = (bf*)(ws + 20971520);              // 39,321,600 B
    bf* woutb = (bf*)(ws + 60293120);              // 13,107,200 B
    bf* qkvb  = (bf*)(ws + 73400320);              // 62,914,560 B
    bf* vtb   = (bf*)(ws + 136314880);             // 20,971,520 B -> total 157,286,400
    bf* attnb = xb;                                // alias: x consumed by gemm1

    cvt_all<<<2048, 256, 0, stream>>>(x, Wqkv, Wout, xb, wqkvb, woutb);
    gemm256<true ><<<dim3(FTOT/256,  MTOT/256), 512, 0, stream>>>(xb, wqkvb, bqkv, qkvb, MTOT, FTOT, EMBED);
    repack_vt<<<dim3(SEQ/64, HDIM/64, BATCH*HEADS), 256, 0, stream>>>(qkvb, vtb);
    attn_fwd<<<dim3(SEQ/128, BATCH*HEADS), 512, 0, stream>>>(qkvb, vtb, attnb);
    gemm256<false><<<dim3(EMBED/256, MTOT/256), 512, 0, stream>>>(attnb, woutb, bout, out, MTOT, EMBED, EMBED);
}

// Round 19
// 406.583 us; speedup vs baseline: 4.8315x; 1.0081x over previous
//
#include <hip/hip_runtime.h>

#define EMBED 2560
#define HEADS 8
#define HDIM  320
#define BATCH 2
#define SEQ   2048
#define MTOT  (BATCH*SEQ)   // 4096
#define FTOT  (3*EMBED)     // 7680

using bf = __bf16;
typedef __bf16 bf16x8 __attribute__((ext_vector_type(8)));
typedef float  f32x4  __attribute__((ext_vector_type(4)));
typedef short  s16x8  __attribute__((ext_vector_type(8)));
typedef float  f32x4v __attribute__((ext_vector_type(4)));

__device__ __forceinline__ void gl_lds16(const bf* g, bf* l) {
    __builtin_amdgcn_global_load_lds(
        (const __attribute__((address_space(1))) void*)g,
        (__attribute__((address_space(3))) void*)l,
        16, 0, 0);
}

// ---------------- fused fp32 -> bf16 convert ----------------
__global__ void cvt_all(const float* __restrict__ x, const float* __restrict__ wq,
                        const float* __restrict__ wo, bf* __restrict__ xb,
                        bf* __restrict__ wqb, bf* __restrict__ wob) {
    const int N1 = MTOT*EMBED/8, N2 = FTOT*EMBED/8, N3 = EMBED*EMBED/8;
    const int stride = gridDim.x*blockDim.x;
    for (int c = blockIdx.x*blockDim.x + threadIdx.x; c < N1+N2+N3; c += stride) {
        const float* s; bf* d; int o = c;
        if (c < N1)           { s = x;  d = xb;  }
        else if (c < N1+N2)   { s = wq; d = wqb; o = c - N1; }
        else                  { s = wo; d = wob; o = c - N1 - N2; }
        f32x4v a = *reinterpret_cast<const f32x4v*>(s + (size_t)o*8);
        f32x4v b = *reinterpret_cast<const f32x4v*>(s + (size_t)o*8 + 4);
        bf16x8 r;
        r[0]=(bf)a[0]; r[1]=(bf)a[1]; r[2]=(bf)a[2]; r[3]=(bf)a[3];
        r[4]=(bf)b[0]; r[5]=(bf)b[1]; r[6]=(bf)b[2]; r[7]=(bf)b[3];
        *reinterpret_cast<bf16x8*>(d + (size_t)o*8) = r;
    }
}

// ============ 8-phase 256x256 NT GEMM (r8 schedule, BK=64, 3-bit swizzle) ============
// XCD supertile raster ONLY for the QKV grid (30x16); proj (10x16) uses chunked swizzle.
template<bool OUTBF>
__global__ __launch_bounds__(512, 2)
void gemm256(const bf* __restrict__ A, const bf* __restrict__ B,
             const float* __restrict__ bias, void* __restrict__ Cp,
             int M, int N, int K) {
    __shared__ __align__(16) bf AsL[2][2][8192];
    __shared__ __align__(16) bf BsL[2][2][8192];
    const int tid = threadIdx.x, lane = tid & 63, wid = tid >> 6;
    const int wr = wid >> 2, wc = wid & 3;
    const int l15 = lane & 15, l4 = lane >> 4;

    int mb, nb;
    const int i = blockIdx.y*gridDim.x + blockIdx.x;
    if ((gridDim.y == 16) && (gridDim.x == 30)) {
        const int xcd = i & 7, j = i >> 3;
        const int pc = xcd & 1, pr = xcd >> 1;
        nb = pc*(gridDim.x >> 1) + (j >> 2);
        mb = pr*4 + (j & 3);
    } else {
        const int nwg = gridDim.x*gridDim.y;
        int bid = ((nwg & 7) == 0) ? (i & 7)*(nwg >> 3) + (i >> 3) : i;
        mb = bid / gridDim.x; nb = bid % gridDim.x;
    }
    const int m0 = mb*256, n0 = nb*256;
    const int NT = K >> 6;

    unsigned aOff[2];
    #pragma unroll
    for (int j = 0; j < 2; ++j) {
        int q = (wid*2 + j)*64 + lane;
        int r = q >> 3, c = q & 7;
        aOff[j] = (unsigned)r*K + (unsigned)((c ^ (r & 7))*8);
    }
    const bf* Ap = A + (size_t)m0*K;
    const bf* Bp = B + (size_t)n0*K;

    auto stA = [&](int bb, int h, int kt) {
        bf* d = &AsL[bb][h][wid*1024];
        const bf* s = Ap + (size_t)h*128*K + (size_t)kt*64;
        gl_lds16(s + aOff[0], d);
        gl_lds16(s + aOff[1], d + 512);
    };
    auto stB = [&](int bb, int h, int kt) {
        bf* d = &BsL[bb][h][wid*1024];
        const bf* s = Bp + (size_t)h*128*K + (size_t)kt*64;
        gl_lds16(s + aOff[0], d);
        gl_lds16(s + aOff[1], d + 512);
    };

    f32x4 acc[8][4] = {};
    bf16x8 aR[4][2], bR0[2][2], bR1[2][2];

    stB(0,0,0); stB(0,1,0); stA(0,0,0); stA(0,1,0); stB(1,0,1); stB(1,1,1);
    asm volatile("s_waitcnt vmcnt(4)" ::: "memory");
    __builtin_amdgcn_s_barrier();

    const int brow0 = (wc & 1)*64;
    for (int kt = 0; kt < NT; ++kt) {
        const int bb = kt & 1;
        const bf* Ab = &AsL[bb][wr][0];
        const bf* Bb = &BsL[bb][wc >> 1][0];

        // ---- phase 1
        #pragma unroll
        for (int mi = 0; mi < 4; ++mi)
            #pragma unroll
            for (int kk = 0; kk < 2; ++kk) {
                int r = mi*16 + l15;
                int kg = kk*4 + l4;
                aR[mi][kk] = *reinterpret_cast<const bf16x8*>(&Ab[r*64 + ((kg ^ (r & 7))*8)]);
            }
        #pragma unroll
        for (int ni = 0; ni < 2; ++ni)
            #pragma unroll
            for (int kk = 0; kk < 2; ++kk) {
                int r = brow0 + ni*16 + l15;
                int kg = kk*4 + l4;
                bR0[ni][kk] = *reinterpret_cast<const bf16x8*>(&Bb[r*64 + ((kg ^ (r & 7))*8)]);
            }
        if (kt + 1 < NT) stA(bb^1, 0, kt+1);
        __builtin_amdgcn_s_barrier();
        asm volatile("s_waitcnt lgkmcnt(0)" ::: "memory");
        __builtin_amdgcn_sched_barrier(0);
        __builtin_amdgcn_s_setprio(1);
        #pragma unroll
        for (int mi = 0; mi < 4; ++mi)
            #pragma unroll
            for (int ni = 0; ni < 2; ++ni)
                #pragma unroll
                for (int kk = 0; kk < 2; ++kk)
                    acc[mi][ni] = __builtin_amdgcn_mfma_f32_16x16x32_bf16(aR[mi][kk], bR0[ni][kk], acc[mi][ni], 0, 0, 0);
        __builtin_amdgcn_s_setprio(0);
        __builtin_amdgcn_s_barrier();

        // ---- phase 2
        #pragma unroll
        for (int ni = 0; ni < 2; ++ni)
            #pragma unroll
            for (int kk = 0; kk < 2; ++kk) {
                int r = brow0 + 32 + ni*16 + l15;
                int kg = kk*4 + l4;
                bR1[ni][kk] = *reinterpret_cast<const bf16x8*>(&Bb[r*64 + ((kg ^ (r & 7))*8)]);
            }
        if (kt + 1 < NT) stA(bb^1, 1, kt+1);
        __builtin_amdgcn_s_barrier();
        asm volatile("s_waitcnt lgkmcnt(0)" ::: "memory");
        __builtin_amdgcn_sched_barrier(0);
        __builtin_amdgcn_s_setprio(1);
        #pragma unroll
        for (int mi = 0; mi < 4; ++mi)
            #pragma unroll
            for (int ni = 0; ni < 2; ++ni)
                #pragma unroll
                for (int kk = 0; kk < 2; ++kk)
                    acc[mi][2+ni] = __builtin_amdgcn_mfma_f32_16x16x32_bf16(aR[mi][kk], bR1[ni][kk], acc[mi][2+ni], 0, 0, 0);
        __builtin_amdgcn_s_setprio(0);
        __builtin_amdgcn_s_barrier();

        // ---- phase 3
        #pragma unroll
        for (int mi = 0; mi < 4; ++mi)
            #pragma unroll
            for (int kk = 0; kk < 2; ++kk) {
                int r = 64 + mi*16 + l15;
                int kg = kk*4 + l4;
                aR[mi][kk] = *reinterpret_cast<const bf16x8*>(&Ab[r*64 + ((kg ^ (r & 7))*8)]);
            }
        if (kt + 2 < NT) stB(bb, 0, kt+2);
        __builtin_amdgcn_s_barrier();
        asm volatile("s_waitcnt lgkmcnt(0)" ::: "memory");
        __builtin_amdgcn_sched_barrier(0);
        __builtin_amdgcn_s_setprio(1);
        #pragma unroll
        for (int mi = 0; mi < 4; ++mi)
            #pragma unroll
            for (int ni = 0; ni < 2; ++ni)
                #pragma unroll
                for (int kk = 0; kk < 2; ++kk)
                    acc[4+mi][2+ni] = __builtin_amdgcn_mfma_f32_16x16x32_bf16(aR[mi][kk], bR1[ni][kk], acc[4+mi][2+ni], 0, 0, 0);
        __builtin_amdgcn_s_setprio(0);
        __builtin_amdgcn_s_barrier();

        // ---- phase 4
        if (kt + 2 < NT) stB(bb, 1, kt+2);
        if (kt >= NT-2) asm volatile("s_waitcnt vmcnt(0)" ::: "memory");
        else            asm volatile("s_waitcnt vmcnt(4)" ::: "memory");
        __builtin_amdgcn_s_barrier();
        __builtin_amdgcn_s_setprio(1);
        #pragma unroll
        for (int mi = 0; mi < 4; ++mi)
            #pragma unroll
            for (int ni = 0; ni < 2; ++ni)
                #pragma unroll
                for (int kk = 0; kk < 2; ++kk)
                    acc[4+mi][ni] = __builtin_amdgcn_mfma_f32_16x16x32_bf16(aR[mi][kk], bR0[ni][kk], acc[4+mi][ni], 0, 0, 0);
        __builtin_amdgcn_s_setprio(0);
        __builtin_amdgcn_s_barrier();
    }

    const int cr0 = m0 + wr*128, cc0 = n0 + wc*64;
    #pragma unroll
    for (int NI = 0; NI < 4; ++NI) {
        int colg = cc0 + NI*16 + l15;
        float bv = bias[colg];
        #pragma unroll
        for (int MI = 0; MI < 8; ++MI)
            #pragma unroll
            for (int rr = 0; rr < 4; ++rr) {
                int rowg = cr0 + MI*16 + l4*4 + rr;
                float v = acc[MI][NI][rr] + bv;
                if (OUTBF) ((bf*)Cp)[(size_t)rowg*N + colg] = (bf)v;
                else       ((float*)Cp)[(size_t)rowg*N + colg] = v;
            }
    }
}

// ---------------- V repack: qkv[b,s,2E + h*D + d] -> vt[bh, d, s] ----------------
__global__ void repack_vt(const bf* __restrict__ qkv, bf* __restrict__ vt) {
    __shared__ bf tile[64][72];
    const int bh = blockIdx.z, b = bh >> 3, h = bh & 7;
    const int s0 = blockIdx.x*64, d0 = blockIdx.y*64;
    const int t = threadIdx.x;
    #pragma unroll
    for (int p = 0; p < 2; ++p) {
        int sr = (t >> 3) + p*32, ck = t & 7;
        s16x8 v = *reinterpret_cast<const s16x8*>(
            qkv + ((size_t)(b*SEQ + s0 + sr))*FTOT + 2*EMBED + h*HDIM + d0 + ck*8);
        *reinterpret_cast<s16x8*>(&tile[sr][ck*8]) = v;
    }
    __syncthreads();
    #pragma unroll
    for (int p = 0; p < 2; ++p) {
        int dr = (t >> 3) + p*32, ck = t & 7;
        bf16x8 r;
        #pragma unroll
        for (int j = 0; j < 8; ++j) r[j] = tile[ck*8 + j][dr];
        *reinterpret_cast<bf16x8*>(vt + ((size_t)bh*HDIM + d0 + dr)*SEQ + s0 + ck*8) = r;
    }
}

// ---------------- flash attention (r18 structure + XCD-bh binding) ----------------
// grid 256 blocks; launched index li: xcd=li&7 owns bh {2*xcd, 2*xcd+1} -- all blocks
// sharing a bh's 2.5MB K/V stream land on one XCD's L2 (FETCH 174->~90MB predicted).
__global__ __launch_bounds__(512, 2)
void attn_fwd(const bf* __restrict__ qkv, const bf* __restrict__ vt, bf* __restrict__ aout) {
    __shared__ bf Kls[2][32*320];
    __shared__ bf Vls[2][320*32];
    __shared__ bf Ps[8][16][40];
    const int li = blockIdx.y*gridDim.x + blockIdx.x;
    const int xcd = li & 7, j = li >> 3;          // j in 0..31
    const int bh = 2*xcd + (j & 1), qt = j >> 1;  // bijective: bh 0..15, qt 0..15
    const int b = bh >> 3, h = bh & 7;
    const int tid = threadIdx.x, lane = tid & 63, wid = tid >> 6;
    const int qw = qt*128 + wid*16;
    const int l15 = lane & 15, l4 = lane >> 4;
    const float scale = 0.05590169944f;

    const bf* gsrc[5];
    int ldsoff[5];
    size_t step;
    if (wid < 4) {
        step = (size_t)32*FTOT;
        #pragma unroll
        for (int i = 0; i < 5; ++i) {
            int g = wid*5 + i;
            int q = g*64 + lane;
            int r = q/40, cl = q - r*40;
            int cg = cl ^ (r & 7);
            gsrc[i] = qkv + (size_t)(b*SEQ + r)*FTOT + EMBED + h*HDIM + cg*8;
            ldsoff[i] = g*512;
        }
    } else {
        step = 32;
        #pragma unroll
        for (int i = 0; i < 5; ++i) {
            int g = wid*5 + i - 20;
            int q = g*64 + lane;
            int row = q >> 2, cl = q & 3;
            int cg = cl ^ ((row >> 1) & 3);
            gsrc[i] = vt + (size_t)bh*HDIM*SEQ + (size_t)row*SEQ + cg*8;
            ldsoff[i] = g*512;
        }
    }

    bf16x8 qf[10];
    const bf* qbase = qkv + ((size_t)(b*SEQ + qw + l15))*FTOT + h*HDIM + l4*8;
    #pragma unroll
    for (int d = 0; d < 10; ++d) qf[d] = *reinterpret_cast<const bf16x8*>(qbase + d*32);

    f32x4 o[20] = {};
    float mrow[4], lsum[4];
    #pragma unroll
    for (int r = 0; r < 4; ++r) { mrow[r] = -1e30f; lsum[r] = 0.f; }

    const int r7  = l15 & 7;
    const int vsw = (l4 ^ ((l15 >> 1) & 3))*8;

    {
        bf* lb = (wid < 4) ? &Kls[0][0] : &Vls[0][0];
        #pragma unroll
        for (int i = 0; i < 5; ++i) { gl_lds16(gsrc[i], lb + ldsoff[i]); gsrc[i] += step; }
    }
    __syncthreads();

    for (int kt = 0; kt < SEQ/32; ++kt) {
        const int bb = kt & 1;
        if (kt + 1 < SEQ/32) {
            bf* lb = (wid < 4) ? &Kls[bb^1][0] : &Vls[bb^1][0];
            #pragma unroll
            for (int i = 0; i < 5; ++i) { gl_lds16(gsrc[i], lb + ldsoff[i]); gsrc[i] += step; }
        }
        const bf* Kb = &Kls[bb][0];
        const bf* Vb = &Vls[bb][0];

        f32x4 sc[2] = {};
        #pragma unroll
        for (int kb = 0; kb < 2; ++kb) {
            const int Rbase = (kb*16 + l15)*320;
            #pragma unroll
            for (int d = 0; d < 10; ++d) {
                int c = (d*4 + l4) ^ r7;
                bf16x8 kf = *reinterpret_cast<const bf16x8*>(&Kb[Rbase + c*8]);
                sc[kb] = __builtin_amdgcn_mfma_f32_16x16x32_bf16(qf[d], kf, sc[kb], 0, 0, 0);
            }
        }

        float tmax[4];
        bool need = false;
        #pragma unroll
        for (int r = 0; r < 4; ++r) {
            float v = fmaxf(sc[0][r], sc[1][r])*scale;
            v = fmaxf(v, __shfl_xor(v, 1));
            v = fmaxf(v, __shfl_xor(v, 2));
            v = fmaxf(v, __shfl_xor(v, 4));
            v = fmaxf(v, __shfl_xor(v, 8));
            tmax[r] = v;
            need = need || (v > mrow[r] + 8.f);
        }
        if (__any(need)) {
            float alpha[4];
            #pragma unroll
            for (int r = 0; r < 4; ++r) {
                float nm = fmaxf(mrow[r], tmax[r]);
                alpha[r] = __expf(mrow[r] - nm);
                mrow[r] = nm;
                lsum[r] *= alpha[r];
            }
            #pragma unroll
            for (int c = 0; c < 20; ++c)
                #pragma unroll
                for (int r = 0; r < 4; ++r) o[c][r] *= alpha[r];
        }

        float ps[2][4];
        #pragma unroll
        for (int r = 0; r < 4; ++r) {
            float p0 = __expf(sc[0][r]*scale - mrow[r]);
            float p1 = __expf(sc[1][r]*scale - mrow[r]);
            ps[0][r] = p0; ps[1][r] = p1;
            lsum[r] += p0 + p1;
        }

        #pragma unroll
        for (int kb = 0; kb < 2; ++kb)
            #pragma unroll
            for (int r = 0; r < 4; ++r)
                Ps[wid][l4*4 + r][kb*16 + l15] = (bf)ps[kb][r];

        bf16x8 pf = *reinterpret_cast<const bf16x8*>(&Ps[wid][l15][l4*8]);
        #pragma unroll
        for (int c = 0; c < 20; ++c) {
            bf16x8 vf = *reinterpret_cast<const bf16x8*>(&Vb[(c*16 + l15)*32 + vsw]);
            o[c] = __builtin_amdgcn_mfma_f32_16x16x32_bf16(pf, vf, o[c], 0, 0, 0);
        }
        __syncthreads();
    }

    float inv[4];
    #pragma unroll
    for (int r = 0; r < 4; ++r) {
        float s = lsum[r];
        s += __shfl_xor(s, 1);
        s += __shfl_xor(s, 2);
        s += __shfl_xor(s, 4);
        s += __shfl_xor(s, 8);
        inv[r] = 1.f/s;
    }
    #pragma unroll
    for (int c = 0; c < 20; ++c)
        #pragma unroll
        for (int r = 0; r < 4; ++r) {
            size_t idx = ((size_t)(b*SEQ + qw + l4*4 + r))*EMBED + h*HDIM + c*16 + l15;
            aout[idx] = (bf)(o[c][r]*inv[r]);
        }
}

// ---------------- launch ----------------
extern "C" void kernel_launch(void* const* d_in, const int* in_sizes, int n_in,
                              void* d_out, int out_size, void* d_ws, size_t ws_size,
                              hipStream_t stream) {
    const float* x    = (const float*)d_in[0];
    const float* Wqkv = (const float*)d_in[1];
    const float* bqkv = (const float*)d_in[2];
    const float* Wout = (const float*)d_in[3];
    const float* bout = (const float*)d_in[4];
    float* out = (float*)d_out;

    char* ws = (char*)d_ws;
    bf* xb    = (bf*)(ws);                         // 20,971,520 B
    bf* wqkvb = (bf*)(ws + 20971520);              // 39,321,600 B
    bf* woutb = (bf*)(ws + 60293120);              // 13,107,200 B
    bf* qkvb  = (bf*)(ws + 73400320);              // 62,914,560 B
    bf* vtb   = (bf*)(ws + 136314880);             // 20,971,520 B -> total 157,286,400
    bf* attnb = xb;                                // alias: x consumed by gemm1

    cvt_all<<<2048, 256, 0, stream>>>(x, Wqkv, Wout, xb, wqkvb, woutb);
    gemm256<true ><<<dim3(FTOT/256,  MTOT/256), 512, 0, stream>>>(xb, wqkvb, bqkv, qkvb, MTOT, FTOT, EMBED);
    repack_vt<<<dim3(SEQ/64, HDIM/64, BATCH*HEADS), 256, 0, stream>>>(qkvb, vtb);
    attn_fwd<<<dim3(16, 16), 512, 0, stream>>>(qkvb, vtb, attnb);
    gemm256<false><<<dim3(EMBED/256, MTOT/256), 512, 0, stream>>>(attnb, woutb, bout, out, MTOT, EMBED, EMBED);
}